// Round 11
// baseline (150.315 us; speedup 1.0000x reference)
//
#include <hip/hip_runtime.h>
#include <hip/hip_bf16.h>
#include <stdint.h>
#include <stddef.h>

constexpr int Bc = 2;
constexpr int Sc = 4096;
constexpr int Dc = 512;
constexpr int Hc = 8;
constexpr int Wc = 32;

using bf16_t = __bf16;
using f16_t  = _Float16;
typedef __attribute__((ext_vector_type(8))) __bf16 bf16x8;
typedef __attribute__((ext_vector_type(4))) __bf16 bf16x4;
typedef __attribute__((ext_vector_type(2))) __bf16 bf16x2;
typedef __attribute__((ext_vector_type(8))) _Float16 f16x8;
typedef __attribute__((ext_vector_type(2))) _Float16 f16x2;
typedef __attribute__((ext_vector_type(4))) float f32x4;

__device__ __forceinline__ void async_copy16(const void* g, void* l) {
    __builtin_amdgcn_global_load_lds(
        (const __attribute__((address_space(1))) void*)g,
        (__attribute__((address_space(3))) void*)l,
        16, 0, 0);
}

// All input conversions in one launch (inputs fp32 — measured round 7).
// Blocks 0..4095: x (4 elem/thread). Blocks 4096..5119: the 4 weights.
__global__ void convert_all(const float* __restrict__ x,
                            const float* __restrict__ wq, const float* __restrict__ wk,
                            const float* __restrict__ wv, const float* __restrict__ wo,
                            bf16_t* __restrict__ xc, bf16_t* __restrict__ dq,
                            bf16_t* __restrict__ dk, bf16_t* __restrict__ dv,
                            bf16_t* __restrict__ dwo) {
    const int blk = blockIdx.x;
    const float* s; bf16_t* d; int base;
    if (blk < 4096) { s = x; d = xc; base = blk * 1024; }
    else {
        const int r = blk - 4096, which = r >> 8;
        s = (which == 0) ? wq : (which == 1) ? wk : (which == 2) ? wv : wo;
        d = (which == 0) ? dq : (which == 1) ? dk : (which == 2) ? dv : dwo;
        base = (r & 255) * 1024;
    }
    const int i = base + threadIdx.x * 4;
    const float4 v = *(const float4*)(s + i);
    bf16x4 o; o[0] = (bf16_t)v.x; o[1] = (bf16_t)v.y;
    o[2] = (bf16_t)v.z; o[3] = (bf16_t)v.w;
    *(bf16x4*)(d + i) = o;
}

// C = A @ B^T (verified rounds 3-10). nPerB>0: virtual B=[B0;B1;B2].
// OMODE: 0 = bf16 out, 1 = f32 out, 2 = f16 out.
template<int BM, int BN, int TM, int TN, int OMODE>
__global__ __launch_bounds__(256) void gemm_bt(
    const bf16_t* __restrict__ A, int lda,
    const bf16_t* __restrict__ B0, const bf16_t* __restrict__ B1,
    const bf16_t* __restrict__ B2, int ldb, int nPerB,
    void* __restrict__ C, int ldc, int K)
{
    constexpr int BK = 32;
    __shared__ __align__(1024) bf16_t Alds[BM * BK];
    __shared__ __align__(1024) bf16_t Blds[BN * BK];

    const int tid  = threadIdx.x;
    const int lane = tid & 63;
    const int wv   = tid >> 6;
    const int wm   = wv >> 1;
    const int wn   = wv & 1;
    const int r    = lane & 15;
    const int q4   = lane >> 4;

    const int blkM = blockIdx.x * BM;
    const int colC = blockIdx.y * BN;

    const bf16_t* Bp = B0;
    int nB = colC;
    if (nPerB > 0) {
        int wsel = colC / nPerB;
        nB = colC - wsel * nPerB;
        Bp = (wsel == 0) ? B0 : (wsel == 1) ? B1 : B2;
    }

    f32x4 acc[TM][TN];
    const f32x4 fzero = {0.f, 0.f, 0.f, 0.f};
    #pragma unroll
    for (int i = 0; i < TM; ++i)
        #pragma unroll
        for (int j = 0; j < TN; ++j) acc[i][j] = fzero;

    constexpr int A_LOADS = (BM * BK * 2) / (256 * 16);
    constexpr int B_LOADS = (BN * BK * 2) / (256 * 16);

    for (int kk = 0; kk < K; kk += BK) {
        __syncthreads();
        #pragma unroll
        for (int i = 0; i < A_LOADS; ++i) {
            int off  = i * 4096 + tid * 16;
            int row  = off >> 6;
            int colb = off & 63;
            const char* g = (const char*)A + ((size_t)(blkM + row) * lda + kk) * 2 + colb;
            async_copy16(g, (char*)Alds + off);
        }
        #pragma unroll
        for (int i = 0; i < B_LOADS; ++i) {
            int off  = i * 4096 + tid * 16;
            int row  = off >> 6;
            int colb = off & 63;
            const char* g = (const char*)Bp + ((size_t)(nB + row) * ldb + kk) * 2 + colb;
            async_copy16(g, (char*)Blds + off);
        }
        __syncthreads();

        bf16x8 af[TM], bfr[TN];
        #pragma unroll
        for (int mt = 0; mt < TM; ++mt)
            af[mt] = *(const bf16x8*)&Alds[(wm * TM * 16 + mt * 16 + r) * BK + q4 * 8];
        #pragma unroll
        for (int nt = 0; nt < TN; ++nt)
            bfr[nt] = *(const bf16x8*)&Blds[(wn * TN * 16 + nt * 16 + r) * BK + q4 * 8];

        #pragma unroll
        for (int mt = 0; mt < TM; ++mt)
            #pragma unroll
            for (int nt = 0; nt < TN; ++nt)
                acc[mt][nt] = __builtin_amdgcn_mfma_f32_16x16x32_bf16(
                    af[mt], bfr[nt], acc[mt][nt], 0, 0, 0);
    }

    #pragma unroll
    for (int mt = 0; mt < TM; ++mt) {
        #pragma unroll
        for (int nt = 0; nt < TN; ++nt) {
            int rr0 = blkM + wm * TM * 16 + mt * 16 + q4 * 4;
            int cc  = colC + wn * TN * 16 + nt * 16 + r;
            #pragma unroll
            for (int i = 0; i < 4; ++i) {
                size_t o = (size_t)(rr0 + i) * ldc + cc;
                if constexpr (OMODE == 1)      ((float*)C)[o]  = acc[mt][nt][i];
                else if constexpr (OMODE == 2) ((f16_t*)C)[o]  = (f16_t)acc[mt][nt][i];
                else                           ((bf16_t*)C)[o] = (bf16_t)acc[mt][nt][i];
            }
        }
    }
}

// Neighbor attention, one wave per (b,h,s). QKV rows: [Q|K|V] f16, 3072 B.
// Phase 1: lane pair (w = lane>>1, half = lane&1): q.k via v_dot2_f32_f16
//          (16 fdot2 replace ~96 cvt+fma); butterfly softmax in registers.
// Phase 3: lane = (nh = lane>>5, d2 = lane&31): dims {2d2, 2d2+1} over 16
//          neighbors, dword V loads, f32 fma; shuffle-merge + bf16x2 store.
__global__ __launch_bounds__(256) void attn_fast(
    const f16_t* __restrict__ QKV,
    const int*   __restrict__ nidx,
    bf16_t*      __restrict__ attn_out)
{
    __shared__ __align__(16) float wa_lds[4][64];  // 32 x (off_bits, weight)
    const int lane = threadIdx.x & 63;
    const int wv   = threadIdx.x >> 6;

    // XCD swizzle: contiguous s-range per XCD for gather L2 locality.
    const int bi  = blockIdx.x;
    const int blk = (bi & 7) * 2048 + (bi >> 3);
    const int wg  = blk * 4 + wv;                  // ((b*8+h)<<12) + s
    const int s = wg & (Sc - 1);
    const int h = (wg >> 12) & (Hc - 1);
    const int b = wg >> 15;
    const size_t row = (size_t)b * Sc + s;

    const int w    = lane >> 1;
    const int half = lane & 1;
    const int t    = nidx[s * Wc + w];

    const char* qkvB = (const char*)QKV;
    const char* Qptr = qkvB + row * 3072 + h * 128 + half * 64;
    const char* Kptr = qkvB + ((size_t)b * Sc + t) * 3072 + 1024 + h * 128 + half * 64;

    f16x8 q8[4], k8[4];
    #pragma unroll
    for (int i = 0; i < 4; ++i) {
        q8[i] = *(const f16x8*)(Qptr + 16 * i);
        k8[i] = *(const f16x8*)(Kptr + 16 * i);
    }
    float p = 0.f;
    #pragma unroll
    for (int i = 0; i < 4; ++i) {
        #pragma unroll
        for (int j = 0; j < 4; ++j) {
            f16x2 qa; qa[0] = q8[i][2 * j]; qa[1] = q8[i][2 * j + 1];
            f16x2 kb; kb[0] = k8[i][2 * j]; kb[1] = k8[i][2 * j + 1];
            p = __builtin_amdgcn_fdot2(qa, kb, p, false);
        }
    }
    p += __shfl_xor(p, 1);                         // full 64-dot in both pair lanes
    p *= 0.125f;                                   // 1/sqrt(64)

    // Butterfly softmax over the 32 lane-pairs.
    float mx = p;
    #pragma unroll
    for (int m = 2; m <= 32; m <<= 1) mx = fmaxf(mx, __shfl_xor(mx, m));
    const float e = __expf(p - mx);
    float sum = e;
    #pragma unroll
    for (int m = 2; m <= 32; m <<= 1) sum += __shfl_xor(sum, m);
    const float a = e / sum;

    if (half == 0) {
        wa_lds[wv][2 * w]     = __int_as_float(t * 3072);
        wa_lds[wv][2 * w + 1] = a;
    }
    __syncthreads();

    // Phase 3. Wave-uniform 64-bit V base; 32-bit per-lane voffset.
    const int d2 = lane & 31;                      // dims 2*d2, 2*d2+1
    const int nh = lane >> 5;                      // neighbors nh*16 .. nh*16+15
    const float* chunkp = &wa_lds[wv][nh * 32];
    const char* Vb = qkvB + (size_t)b * Sc * 3072 + 2048 + h * 128;
    const int dk = d2 * 4;

    float acc0 = 0.f, acc1 = 0.f;
    #pragma unroll
    for (int j = 0; j < 8; ++j) {
        const float4 c = *(const float4*)(chunkp + 4 * j);
        {
            const unsigned v = *(const unsigned*)(Vb + __float_as_int(c.x) + dk);
            const f16x2 v2 = __builtin_bit_cast(f16x2, v);
            acc0 = fmaf(c.y, (float)v2[0], acc0);
            acc1 = fmaf(c.y, (float)v2[1], acc1);
        }
        {
            const unsigned v = *(const unsigned*)(Vb + __float_as_int(c.z) + dk);
            const f16x2 v2 = __builtin_bit_cast(f16x2, v);
            acc0 = fmaf(c.w, (float)v2[0], acc0);
            acc1 = fmaf(c.w, (float)v2[1], acc1);
        }
    }
    acc0 += __shfl_xor(acc0, 32);
    acc1 += __shfl_xor(acc1, 32);
    if (nh == 0) {
        bf16x2 pr; pr[0] = (bf16_t)acc0; pr[1] = (bf16_t)acc1;
        *(bf16x2*)((char*)attn_out + row * 1024 + h * 128 + dk) = pr;
    }
}

extern "C" void kernel_launch(void* const* d_in, const int* in_sizes, int n_in,
                              void* d_out, int out_size, void* d_ws, size_t ws_size,
                              hipStream_t stream) {
    (void)in_sizes; (void)n_in; (void)out_size; (void)ws_size;
    const int* nidx = (const int*)d_in[5];
    const int M = Bc * Sc;                        // 8192
    float* out = (float*)d_out;                   // fp32 output (round-7 finding)

    char* w = (char*)d_ws;
    bf16_t* xc   = (bf16_t*)(w + 256);            // 8 MB
    bf16_t* Wqc  = xc  + 4194304;                 // 0.5 MB each
    bf16_t* Wkc  = Wqc + 262144;
    bf16_t* Wvc  = Wkc + 262144;
    bf16_t* Woc  = Wvc + 262144;
    f16_t*  qkv  = (f16_t*)(Woc + 262144);        // 24 MB, f16
    bf16_t* attnS = xc;                           // reuse x-buffer after GEMM1

    convert_all<<<5120, 256, 0, stream>>>(
        (const float*)d_in[0], (const float*)d_in[1], (const float*)d_in[2],
        (const float*)d_in[3], (const float*)d_in[4],
        xc, Wqc, Wkc, Wvc, Woc);

    // Fused QKV projection: M=8192, N=1536, K=512 (f16 out for fdot2).
    gemm_bt<128, 128, 4, 4, 2><<<dim3(M / 128, 1536 / 128), 256, 0, stream>>>(
        xc, Dc, Wqc, Wkc, Wvc, Dc, 512, qkv, 1536, Dc);

    // Neighbor attention.
    attn_fast<<<(Bc * Hc * Sc) / 4, 256, 0, stream>>>(qkv, nidx, attnS);

    // Output projection: M=8192, N=512, K=512 -> fp32 d_out.
    gemm_bt<128, 64, 4, 2, 1><<<dim3(M / 128, 512 / 64), 256, 0, stream>>>(
        attnS, 512, Woc, Woc, Woc, 512, 0, out, Dc, Dc);
}